// Round 12
// baseline (82.627 us; speedup 1.0000x reference)
//
#include <hip/hip_runtime.h>

// Problem constants
#define NB    16
#define TLEN  1024
#define CCH   128
#define DR    320

typedef _Float16 h8 __attribute__((ext_vector_type(8)));
typedef _Float16 h4 __attribute__((ext_vector_type(4)));
typedef _Float16 h2 __attribute__((ext_vector_type(2)));
typedef float    f4 __attribute__((ext_vector_type(4)));

// async global->LDS, 16 B/lane. LDS dest = readfirstlane(base)+lane*16, LINEAR.
__device__ __forceinline__ void gload16h(const _Float16* g, _Float16* l) {
  __builtin_amdgcn_global_load_lds(
      (const __attribute__((address_space(1))) void*)g,
      (__attribute__((address_space(3))) void*)l, 16, 0, 0);
}
__device__ __forceinline__ void gload16f(const float* g, float* l) {
  __builtin_amdgcn_global_load_lds(
      (const __attribute__((address_space(1))) void*)g,
      (__attribute__((address_space(3))) void*)l, 16, 0, 0);
}

// ---------------------------------------------------------------------------
// Init: cast x->h0 (f16), weight prep, fblb2 = fb+lb. 1024 blocks.
__global__ __launch_bounds__(256) void k_init(const float* __restrict__ x,
                                              const float* __restrict__ w1,
                                              const float* __restrict__ w2,
                                              const float* __restrict__ linw,
                                              const float* __restrict__ fb,
                                              const float* __restrict__ lb,
                                              _Float16* __restrict__ h0,
                                              _Float16* __restrict__ Wsh,
                                              _Float16* __restrict__ linWh,
                                              float* __restrict__ fblb2) {
  int i = blockIdx.x * 256 + threadIdx.x;     // 0..262143
  const float4* src = (const float4*)x + (size_t)i * 2;
  float4 a = src[0], b = src[1];
  h8 v;
  v[0] = (_Float16)a.x; v[1] = (_Float16)a.y; v[2] = (_Float16)a.z; v[3] = (_Float16)a.w;
  v[4] = (_Float16)b.x; v[5] = (_Float16)b.y; v[6] = (_Float16)b.z; v[7] = (_Float16)b.w;
  *(h8*)(h0 + (size_t)i * 8) = v;

  if (i < 6 * 32768) {
    int c = i & 127, k = (i >> 7) & 1, o = (i >> 8) & 127, i3 = i >> 15;
    const float* srcw = (i3 < 3) ? (w1 + i3 * 32768) : (w2 + (i3 - 3) * 32768);
    Wsh[i] = (_Float16)srcw[(o * 128 + c) * 2 + k];
  }
  if (i < 16384) linWh[i] = (_Float16)linw[i];
  if (i < 98304) fblb2[i] = fb[i] + lb[i];
}

// ---------------------------------------------------------------------------
// gen = r @ fparam_W^T + fb + lb -> Wg[q][o][k][c] f16, q = 3n+G.
// MFMA tall-skinny GEMM, 3-buffer counted-vmcnt pipeline (T3+T4):
// 256 blocks x 384 rows, 12 tiles of 32 rows. Per-wave VMEM issue counts are
// UNIFORM (10 gload16f + 1 h2 store per iter), so B2 waits vmcnt(11):
// drains tile j+2 and older while tile j+3 + this store stay in flight.
__global__ __launch_bounds__(256) void k_gen4(const float* __restrict__ r,
                                              const float* __restrict__ fW,
                                              const float* __restrict__ fblb2,
                                              _Float16* __restrict__ wg) {
  __shared__ alignas(16) float buf[3][32 * DR];   // 122,880 B
  __shared__ alignas(16) float csc[4][16][16];    // 4,096 B
  __shared__ alignas(16) float fbl[384];          // 1,536 B  (total 128,512)
  const int tid = threadIdx.x;
  const size_t rbase = (size_t)blockIdx.x * 384;

  const int l = tid & 63, w = tid >> 6;
  const int l15 = l & 15, lh = l >> 4;
  const int rt = w >> 1, kh = w & 1;

  // r -> registers (ordinary loads; 20 KB total, L2-hot)
  f4 rx[5], ry[5];
  const float* rp = r + l15 * DR + kh * 160 + lh * 8;
#pragma unroll
  for (int cb = 0; cb < 5; cb++) {
    rx[cb] = *(const f4*)(rp + cb * 32);
    ry[cb] = *(const f4*)(rp + cb * 32 + 4);
  }
  // block's fblb slice -> LDS (once); partial wave OK (prologue drains vmcnt(0-ish))
  if (tid < 96) gload16f(fblb2 + rbase + tid * 4, fbl + tid * 4);
  // tiles 0..2
#pragma unroll
  for (int t = 0; t < 3; t++) {
    const float* s = fW + (rbase + (size_t)t * 32) * DR;
#pragma unroll
    for (int i = 0; i < 10; i++) {
      int f = tid + i * 256;
      gload16f(s + (size_t)f * 4, (float*)buf[t] + (size_t)f * 4);
    }
  }
  h8 bfr[5];
#pragma unroll
  for (int cb = 0; cb < 5; cb++) {
    h8 v;
    v[0] = (_Float16)rx[cb][0]; v[1] = (_Float16)rx[cb][1];
    v[2] = (_Float16)rx[cb][2]; v[3] = (_Float16)rx[cb][3];
    v[4] = (_Float16)ry[cb][0]; v[5] = (_Float16)ry[cb][1];
    v[6] = (_Float16)ry[cb][2]; v[7] = (_Float16)ry[cb][3];
    bfr[cb] = v;
  }
  // newest 20 = tiles 1,2 stay in flight; r/fbl/tile0 drained
  asm volatile("s_waitcnt vmcnt(20) lgkmcnt(0)" ::: "memory");
  __builtin_amdgcn_s_barrier();
  __builtin_amdgcn_sched_barrier(0);

  const int rn = tid >> 4, rk = (tid >> 3) & 1, rcq = tid & 7;

  for (int j = 0; j < 12; j++) {
    const float* bp = (const float*)buf[j % 3];
    f4 acc = {0.f, 0.f, 0.f, 0.f};
    const float* arow = bp + (rt * 16 + l15) * DR + kh * 160 + lh * 8;
#pragma unroll
    for (int cb = 0; cb < 5; cb++) {
      f4 x = *(const f4*)(arow + cb * 32);
      f4 y = *(const f4*)(arow + cb * 32 + 4);
      h8 a;
      a[0] = (_Float16)x[0]; a[1] = (_Float16)x[1];
      a[2] = (_Float16)x[2]; a[3] = (_Float16)x[3];
      a[4] = (_Float16)y[0]; a[5] = (_Float16)y[1];
      a[6] = (_Float16)y[2]; a[7] = (_Float16)y[3];
      acc = __builtin_amdgcn_mfma_f32_16x16x32_f16(a, bfr[cb], acc, 0, 0, 0);
    }
#pragma unroll
    for (int rr = 0; rr < 4; rr++) csc[w][lh * 4 + rr][l15] = acc[rr];

    // B1: csc visible (LDS-only fence; DMA stays in flight)
    asm volatile("s_waitcnt lgkmcnt(0)" ::: "memory");
    __builtin_amdgcn_s_barrier();
    __builtin_amdgcn_sched_barrier(0);

    // repack: ALL 256 threads, exactly one 4-B h2 store each (vmcnt-uniform)
    {
      const unsigned g32 = (unsigned)(rbase + (size_t)j * 32);
      const unsigned G = g32 >> 15, o = (g32 >> 8) & 127u, c0 = (g32 & 255u) >> 1;
      h2 v2;
#pragma unroll
      for (int i = 0; i < 2; i++) {
        int rl32 = (rcq * 2 + i) * 2 + rk;
        int hp = (rl32 >> 4) * 2, rr2 = rl32 & 15;
        float s = csc[hp][rr2][rn] + csc[hp + 1][rr2][rn] + fbl[j * 32 + rl32];
        v2[i] = (_Float16)s;
      }
      unsigned q = 3u * (unsigned)rn + G;
      *(h2*)&wg[(((size_t)q * 128 + o) * 2 + rk) * 128 + c0 + rcq * 2] = v2;
    }

    // prefetch tile j+3 into the buffer just retired
    if (j <= 8) {
      float* dstb = (float*)buf[j % 3];
      const float* src = fW + (rbase + (size_t)(j + 3) * 32) * DR;
#pragma unroll
      for (int i = 0; i < 10; i++) {
        int f = tid + i * 256;
        gload16f(src + (size_t)f * 4, dstb + (size_t)f * 4);
      }
    }

    // B2: counted wait — keep newest tile + this store in flight
    if (j < 10)
      asm volatile("s_waitcnt vmcnt(11) lgkmcnt(0)" ::: "memory");
    else if (j == 10)
      asm volatile("s_waitcnt vmcnt(2) lgkmcnt(0)" ::: "memory");
    else
      asm volatile("s_waitcnt vmcnt(0) lgkmcnt(0)" ::: "memory");
    __builtin_amdgcn_s_barrier();
    __builtin_amdgcn_sched_barrier(0);
  }
}

// ---------------------------------------------------------------------------
// Fused shared residual pair (verified r10).
template <int D>   // 1, 2, 4
__global__ __launch_bounds__(256) void k_pair(const _Float16* __restrict__ in,
                                              _Float16* __restrict__ out,
                                              const _Float16* __restrict__ w1p,
                                              const _Float16* __restrict__ w2p,
                                              const float* __restrict__ b1p,
                                              const float* __restrict__ b2p) {
  constexpr int HA = 16;
  constexpr int HI = HA + D;
  constexpr int RIN = 80 + D;
  __shared__ _Float16 hin_l[RIN * 128];
  __shared__ _Float16 a_l[80 * 128];

  const int tid = threadIdx.x;
  const int n = blockIdx.y, t0 = blockIdx.x * 64;
  const _Float16* inN = in + (size_t)n * (TLEN * CCH);

  if (blockIdx.x == 0) {
    for (int f = tid; f < HI * 16; f += 256)
      *(int4*)(hin_l + (size_t)f * 8) = make_int4(0, 0, 0, 0);
    for (int f = HI * 16 + tid; f < RIN * 16; f += 256) {
      int p = f >> 4, l16 = f & 15;
      int c8 = (l16 ^ (p & 15)) << 3;
      gload16h(inN + (t0 - HI + p) * 128 + c8, hin_l + f * 8);
    }
  } else {
    for (int f = tid; f < RIN * 16; f += 256) {
      int p = f >> 4, l16 = f & 15;
      int c8 = (l16 ^ (p & 15)) << 3;
      gload16h(inN + (t0 - HI + p) * 128 + c8, hin_l + f * 8);
    }
  }
  __syncthreads();

  const int l = tid & 63, w = tid >> 6;
  const int l15 = l & 15, lh = l >> 4;
  const int o0 = w * 32;

  f4 acc1[2][5] = {};
#pragma unroll
  for (int tap = 0; tap < 2; tap++) {
#pragma unroll
    for (int cb = 0; cb < 4; cb++) {
      const int c0 = cb * 32 + lh * 8;
      h8 a[2], bfr[5];
#pragma unroll
      for (int i2 = 0; i2 < 2; i2++) {
        int o = o0 + i2 * 16 + l15;
        a[i2] = *(const h8*)&w1p[(o * 2 + tap) * 128 + c0];
      }
#pragma unroll
      for (int jt = 0; jt < 5; jt++) {
        int p = jt * 16 + l15 + tap * D;
        int cs = c0 ^ ((p & 15) << 3);
        bfr[jt] = *(const h8*)&hin_l[p * 128 + cs];
      }
#pragma unroll
      for (int i2 = 0; i2 < 2; i2++)
#pragma unroll
        for (int jt = 0; jt < 5; jt++)
          acc1[i2][jt] = __builtin_amdgcn_mfma_f32_16x16x32_f16(
              a[i2], bfr[jt], acc1[i2][jt], 0, 0, 0);
    }
  }
#pragma unroll
  for (int i2 = 0; i2 < 2; i2++) {
    f4 bv = *(const f4*)&b1p[o0 + i2 * 16 + lh * 4];
    const int base8 = o0 + i2 * 16 + (lh >> 1) * 8;
    const int sub = (lh & 1) * 4;
#pragma unroll
    for (int jt = 0; jt < 5; jt++) {
      int p = jt * 16 + l15;
      h4 sv;
      if (blockIdx.x == 0 && jt == 0) {
        sv[0] = sv[1] = sv[2] = sv[3] = (_Float16)0.f;
      } else {
        f4 v = acc1[i2][jt];
#pragma unroll
        for (int rr = 0; rr < 4; rr++) sv[rr] = (_Float16)fmaxf(v[rr] + bv[rr], 0.f);
      }
      *(h4*)&a_l[p * 128 + (base8 ^ ((p & 15) << 3)) + sub] = sv;
    }
  }
  __syncthreads();

  f4 acc2[2][4] = {};
#pragma unroll
  for (int tap = 0; tap < 2; tap++) {
#pragma unroll
    for (int cb = 0; cb < 4; cb++) {
      const int c0 = cb * 32 + lh * 8;
      h8 a[2], bfr[4];
#pragma unroll
      for (int i2 = 0; i2 < 2; i2++) {
        int o = o0 + i2 * 16 + l15;
        a[i2] = *(const h8*)&w2p[(o * 2 + tap) * 128 + c0];
      }
#pragma unroll
      for (int jt = 0; jt < 4; jt++) {
        int pa = jt * 16 + l15 + (HA - D) + tap * D;
        int cs = c0 ^ ((pa & 15) << 3);
        bfr[jt] = *(const h8*)&a_l[pa * 128 + cs];
      }
#pragma unroll
      for (int i2 = 0; i2 < 2; i2++)
#pragma unroll
        for (int jt = 0; jt < 4; jt++)
          acc2[i2][jt] = __builtin_amdgcn_mfma_f32_16x16x32_f16(
              a[i2], bfr[jt], acc2[i2][jt], 0, 0, 0);
    }
  }

  _Float16* outN = out + (size_t)n * (TLEN * CCH);
#pragma unroll
  for (int i2 = 0; i2 < 2; i2++) {
    f4 bv = *(const f4*)&b2p[o0 + i2 * 16 + lh * 4];
    const int base8 = o0 + i2 * 16 + (lh >> 1) * 8;
    const int sub = (lh & 1) * 4;
#pragma unroll
    for (int jt = 0; jt < 4; jt++) {
      int t = t0 + jt * 16 + l15;
      int pr = jt * 16 + l15 + HA + D;
      h4 rv = *(const h4*)&hin_l[pr * 128 + (base8 ^ ((pr & 15) << 3)) + sub];
      f4 v = acc2[i2][jt];
      h4 sv;
#pragma unroll
      for (int rr = 0; rr < 4; rr++) {
        float z = fmaxf(v[rr] + bv[rr], 0.f);
        sv[rr] = (_Float16)fmaxf(z + (float)rv[rr], 0.f);
      }
      *(h4*)&outN[t * 128 + o0 + i2 * 16 + lh * 4] = sv;
    }
  }
}

// ---------------------------------------------------------------------------
// Group conv (verified r10), res from hl.
template <int D>   // 8, 16
__global__ __launch_bounds__(256) void k_gconv(const _Float16* __restrict__ in,
                                               _Float16* __restrict__ out,
                                               const _Float16* __restrict__ wBase) {
  __shared__ _Float16 Wl[256 * 128];
  __shared__ _Float16 hl[(64 + D) * 128];
  const int tid = threadIdx.x;
  const int n = blockIdx.y, t0 = blockIdx.x * 64;
  const _Float16* inN = in + (size_t)n * (TLEN * CCH);
  const _Float16* wp = wBase + (size_t)n * 32768;

  for (int f = tid; f < 4096; f += 256) {
    int row = f >> 4, l16 = f & 15;
    int c8 = (l16 ^ ((row >> 1) & 15)) << 3;
    gload16h(wp + row * 128 + c8, Wl + f * 8);
  }
  if (blockIdx.x == 0) {
    for (int f = tid; f < D * 16; f += 256)
      *(int4*)(hl + (size_t)f * 8) = make_int4(0, 0, 0, 0);
    for (int f = D * 16 + tid; f < (64 + D) * 16; f += 256) {
      int p = f >> 4, l16 = f & 15;
      int c8 = (l16 ^ (p & 15)) << 3;
      gload16h(inN + (t0 - D + p) * 128 + c8, hl + f * 8);
    }
  } else {
    for (int f = tid; f < (64 + D) * 16; f += 256) {
      int p = f >> 4, l16 = f & 15;
      int c8 = (l16 ^ (p & 15)) << 3;
      gload16h(inN + (t0 - D + p) * 128 + c8, hl + f * 8);
    }
  }
  __syncthreads();

  const int l = tid & 63, w = tid >> 6;
  const int l15 = l & 15, lh = l >> 4;
  const int o0 = w * 32;
  f4 acc[2][4] = {};

#pragma unroll
  for (int tap = 0; tap < 2; tap++) {
#pragma unroll
    for (int cb = 0; cb < 4; cb++) {
      const int c0 = cb * 32 + 8 * lh;
      h8 a[2], bfr[4];
#pragma unroll
      for (int i2 = 0; i2 < 2; i2++) {
        int o = o0 + i2 * 16 + l15;
        int cs = c0 ^ ((o & 15) << 3);
        a[i2] = *(const h8*)&Wl[(o * 2 + tap) * 128 + cs];
      }
#pragma unroll
      for (int jt = 0; jt < 4; jt++) {
        int p = jt * 16 + l15 + tap * D;
        int cs = c0 ^ ((p & 15) << 3);
        bfr[jt] = *(const h8*)&hl[p * 128 + cs];
      }
#pragma unroll
      for (int i2 = 0; i2 < 2; i2++)
#pragma unroll
        for (int jt = 0; jt < 4; jt++)
          acc[i2][jt] = __builtin_amdgcn_mfma_f32_16x16x32_f16(
              a[i2], bfr[jt], acc[i2][jt], 0, 0, 0);
    }
  }

  _Float16* outN = out + (size_t)n * (TLEN * CCH);
#pragma unroll
  for (int i2 = 0; i2 < 2; i2++) {
    const int base8 = o0 + i2 * 16 + (lh >> 1) * 8;
    const int sub = (lh & 1) * 4;
#pragma unroll
    for (int jt = 0; jt < 4; jt++) {
      int t = t0 + jt * 16 + l15;
      int pr = jt * 16 + l15 + D;
      h4 rv = *(const h4*)&hl[pr * 128 + (base8 ^ ((pr & 15) << 3)) + sub];
      f4 v = acc[i2][jt];
      h4 sv;
#pragma unroll
      for (int rr = 0; rr < 4; rr++) {
        float z = fmaxf(v[rr], 0.f);
        sv[rr] = (_Float16)fmaxf(z + (float)rv[rr], 0.f);
      }
      *(h4*)&outN[t * 128 + o0 + i2 * 16 + lh * 4] = sv;
    }
  }
}

// ---------------------------------------------------------------------------
// Fused group conv D=32 + final linear (verified r10).
__global__ __launch_bounds__(256) void k_glin(const _Float16* __restrict__ in,
                                              float* __restrict__ outp,
                                              const _Float16* __restrict__ wBase,
                                              const _Float16* __restrict__ linWh,
                                              const float* __restrict__ lbias) {
  constexpr int D = 32;
  __shared__ _Float16 Wl[256 * 128];
  __shared__ _Float16 hl[(64 + D) * 128];
  __shared__ _Float16 a_l[64 * 128];
  const int tid = threadIdx.x;
  const int n = blockIdx.y, t0 = blockIdx.x * 64;
  const _Float16* inN = in + (size_t)n * (TLEN * CCH);
  const _Float16* wp = wBase + (size_t)n * 32768;

  for (int f = tid; f < 4096; f += 256) {
    int row = f >> 4, l16 = f & 15;
    int c8 = (l16 ^ ((row >> 1) & 15)) << 3;
    gload16h(wp + row * 128 + c8, Wl + f * 8);
  }
  if (blockIdx.x == 0) {
    for (int f = tid; f < D * 16; f += 256)
      *(int4*)(hl + (size_t)f * 8) = make_int4(0, 0, 0, 0);
    for (int f = D * 16 + tid; f < (64 + D) * 16; f += 256) {
      int p = f >> 4, l16 = f & 15;
      int c8 = (l16 ^ (p & 15)) << 3;
      gload16h(inN + (t0 - D + p) * 128 + c8, hl + f * 8);
    }
  } else {
    for (int f = tid; f < (64 + D) * 16; f += 256) {
      int p = f >> 4, l16 = f & 15;
      int c8 = (l16 ^ (p & 15)) << 3;
      gload16h(inN + (t0 - D + p) * 128 + c8, hl + f * 8);
    }
  }
  __syncthreads();

  const int l = tid & 63, w = tid >> 6;
  const int l15 = l & 15, lh = l >> 4;
  const int o0 = w * 32;
  f4 acc[2][4] = {};

#pragma unroll
  for (int tap = 0; tap < 2; tap++) {
#pragma unroll
    for (int cb = 0; cb < 4; cb++) {
      const int c0 = cb * 32 + 8 * lh;
      h8 a[2], bfr[4];
#pragma unroll
      for (int i2 = 0; i2 < 2; i2++) {
        int o = o0 + i2 * 16 + l15;
        int cs = c0 ^ ((o & 15) << 3);
        a[i2] = *(const h8*)&Wl[(o * 2 + tap) * 128 + cs];
      }
#pragma unroll
      for (int jt = 0; jt < 4; jt++) {
        int p = jt * 16 + l15 + tap * D;
        int cs = c0 ^ ((p & 15) << 3);
        bfr[jt] = *(const h8*)&hl[p * 128 + cs];
      }
#pragma unroll
      for (int i2 = 0; i2 < 2; i2++)
#pragma unroll
        for (int jt = 0; jt < 4; jt++)
          acc[i2][jt] = __builtin_amdgcn_mfma_f32_16x16x32_f16(
              a[i2], bfr[jt], acc[i2][jt], 0, 0, 0);
    }
  }

#pragma unroll
  for (int i2 = 0; i2 < 2; i2++) {
    const int base8 = o0 + i2 * 16 + (lh >> 1) * 8;
    const int sub = (lh & 1) * 4;
#pragma unroll
    for (int jt = 0; jt < 4; jt++) {
      int p = jt * 16 + l15;
      int pr = p + D;
      h4 rv = *(const h4*)&hl[pr * 128 + (base8 ^ ((pr & 15) << 3)) + sub];
      f4 v = acc[i2][jt];
      h4 sv;
#pragma unroll
      for (int rr = 0; rr < 4; rr++) {
        float z = fmaxf(v[rr], 0.f);
        sv[rr] = (_Float16)fmaxf(z + (float)rv[rr], 0.f);
      }
      *(h4*)&a_l[p * 128 + (base8 ^ (l15 << 3)) + sub] = sv;
    }
  }
  __syncthreads();

  f4 acc3[2][4] = {};
#pragma unroll
  for (int cb = 0; cb < 4; cb++) {
    const int c0 = cb * 32 + lh * 8;
    h8 a[2], bfr[4];
#pragma unroll
    for (int i2 = 0; i2 < 2; i2++) {
      int o = o0 + i2 * 16 + l15;
      a[i2] = *(const h8*)&linWh[o * 128 + c0];
    }
#pragma unroll
    for (int jt = 0; jt < 4; jt++) {
      int p = jt * 16 + l15;
      int cs = c0 ^ ((p & 15) << 3);
      bfr[jt] = *(const h8*)&a_l[p * 128 + cs];
    }
#pragma unroll
    for (int i2 = 0; i2 < 2; i2++)
#pragma unroll
      for (int jt = 0; jt < 4; jt++)
        acc3[i2][jt] = __builtin_amdgcn_mfma_f32_16x16x32_f16(
            a[i2], bfr[jt], acc3[i2][jt], 0, 0, 0);
  }

#pragma unroll
  for (int i2 = 0; i2 < 2; i2++) {
    int o = o0 + i2 * 16 + lh * 4;
    f4 bv = *(const f4*)&lbias[o];
#pragma unroll
    for (int jt = 0; jt < 4; jt++) {
      int t = t0 + jt * 16 + l15;
      f4 v = acc3[i2][jt];
      float4 sv = make_float4(v[0] + bv[0], v[1] + bv[1], v[2] + bv[2], v[3] + bv[3]);
      *(float4*)&outp[((size_t)n * TLEN + t) * CCH + o] = sv;
    }
  }
}

// ---------------------------------------------------------------------------
extern "C" void kernel_launch(void* const* d_in, const int* in_sizes, int n_in,
                              void* d_out, int out_size, void* d_ws, size_t ws_size,
                              hipStream_t stream) {
  const float* x  = (const float*)d_in[0];
  const float* r  = (const float*)d_in[1];
  // d_in[2] = f_out_same_in_size (==1)
  const float* w1 = (const float*)d_in[3];
  const float* b1 = (const float*)d_in[4];
  const float* w2 = (const float*)d_in[5];
  const float* b2 = (const float*)d_in[6];
  const float* fW = (const float*)d_in[7];
  const float* fb = (const float*)d_in[8];
  const float* lb = (const float*)d_in[9];
  const float* lw = (const float*)d_in[10];
  const float* lbias = (const float*)d_in[11];
  float* out = (float*)d_out;

  _Float16* h0    = (_Float16*)d_ws;        // 2,097,152 halves
  _Float16* h1    = h0 + 2097152;           // 2,097,152
  _Float16* Wsh   = h1 + 2097152;           // 393,216
  _Float16* linWh = Wsh + 393216;           // 16,384
  _Float16* Wg    = linWh + 16384;          // 1,572,864
  float*    fblb2 = (float*)(Wg + 1572864); // 98,304 floats

  k_init<<<1024, 256, 0, stream>>>(x, w1, w2, lw, fb, lb, h0, Wsh, linWh, fblb2);
  k_gen4<<<256, 256, 0, stream>>>(r, fW, fblb2, Wg);

  const dim3 cg(16, 16);
  k_pair<1><<<cg, 256, 0, stream>>>(h0, h1, Wsh + 0 * 32768, Wsh + 3 * 32768,
                                    b1, b2);
  k_pair<2><<<cg, 256, 0, stream>>>(h1, h0, Wsh + 1 * 32768, Wsh + 4 * 32768,
                                    b1 + 128, b2 + 128);
  k_pair<4><<<cg, 256, 0, stream>>>(h0, h1, Wsh + 2 * 32768, Wsh + 5 * 32768,
                                    b1 + 256, b2 + 256);
  k_gconv<8> <<<cg, 256, 0, stream>>>(h1, h0, Wg);
  k_gconv<16><<<cg, 256, 0, stream>>>(h0, h1, Wg + 524288);
  k_glin<<<cg, 256, 0, stream>>>(h1, out, Wg + 1048576, linWh, lbias);
}

// Round 14
// 78.044 us; speedup vs baseline: 1.0587x; 1.0587x over previous
//
#include <hip/hip_runtime.h>

// Problem constants
#define NB    16
#define TLEN  1024
#define CCH   128
#define DR    320

typedef _Float16 h8 __attribute__((ext_vector_type(8)));
typedef _Float16 h4 __attribute__((ext_vector_type(4)));
typedef _Float16 h2 __attribute__((ext_vector_type(2)));
typedef float    f4 __attribute__((ext_vector_type(4)));

// async global->LDS, 16 B/lane. LDS dest = readfirstlane(base)+lane*16, LINEAR.
__device__ __forceinline__ void gload16h(const _Float16* g, _Float16* l) {
  __builtin_amdgcn_global_load_lds(
      (const __attribute__((address_space(1))) void*)g,
      (__attribute__((address_space(3))) void*)l, 16, 0, 0);
}
__device__ __forceinline__ void gload16f(const float* g, float* l) {
  __builtin_amdgcn_global_load_lds(
      (const __attribute__((address_space(1))) void*)g,
      (__attribute__((address_space(3))) void*)l, 16, 0, 0);
}

// ---------------------------------------------------------------------------
// Init: cast x->h0 (f16), weight prep, fblb2 = fb+lb. 1024 blocks. (r12 verified)
__global__ __launch_bounds__(256) void k_init(const float* __restrict__ x,
                                              const float* __restrict__ w1,
                                              const float* __restrict__ w2,
                                              const float* __restrict__ linw,
                                              const float* __restrict__ fb,
                                              const float* __restrict__ lb,
                                              _Float16* __restrict__ h0,
                                              _Float16* __restrict__ Wsh,
                                              _Float16* __restrict__ linWh,
                                              float* __restrict__ fblb2) {
  int i = blockIdx.x * 256 + threadIdx.x;     // 0..262143
  const float4* src = (const float4*)x + (size_t)i * 2;
  float4 a = src[0], b = src[1];
  h8 v;
  v[0] = (_Float16)a.x; v[1] = (_Float16)a.y; v[2] = (_Float16)a.z; v[3] = (_Float16)a.w;
  v[4] = (_Float16)b.x; v[5] = (_Float16)b.y; v[6] = (_Float16)b.z; v[7] = (_Float16)b.w;
  *(h8*)(h0 + (size_t)i * 8) = v;

  if (i < 6 * 32768) {
    int c = i & 127, k = (i >> 7) & 1, o = (i >> 8) & 127, i3 = i >> 15;
    const float* srcw = (i3 < 3) ? (w1 + i3 * 32768) : (w2 + (i3 - 3) * 32768);
    Wsh[i] = (_Float16)srcw[(o * 128 + c) * 2 + k];
  }
  if (i < 16384) linWh[i] = (_Float16)linw[i];
  if (i < 98304) fblb2[i] = fb[i] + lb[i];
}

// ---------------------------------------------------------------------------
// Shared structs for the fused gen||pair1 kernel
struct SGen {
  float buf[3][32 * DR];    // 122,880 B
  float csc[4][16][16];     // 4,096 B
  float fbl[512];           // 2,048 B   (total 129,024 B)
};
struct SPair {              // sized for the LARGEST D used (D=4: RIN=84)
  _Float16 hin[84 * 128];
  _Float16 a[80 * 128];
};
union alignas(16) SU { SGen g; SPair p; };

// ---------------------------------------------------------------------------
// gen body: 192 blocks x 512 rows, 16 tiles of 32 rows; 3-buffer pipeline.
// B2 waits vmcnt(20): model-independent count — drains tile j+1's 10 loads
// whether or not stores count toward vmcnt (order pinned by sched_barrier).
__device__ __forceinline__ void gen_body(SGen& S, int bid, int tid,
                                         const float* __restrict__ r,
                                         const float* __restrict__ fW,
                                         const float* __restrict__ fblb2,
                                         _Float16* __restrict__ wg) {
  constexpr int NT = 16;
  const size_t rbase = (size_t)bid * 512;

  const int l = tid & 63, w = tid >> 6;
  const int l15 = l & 15, lh = l >> 4;
  const int rt = w >> 1, kh = w & 1;

  // r -> registers (ordinary loads, L2-hot)
  f4 rx[5], ry[5];
  const float* rp = r + l15 * DR + kh * 160 + lh * 8;
#pragma unroll
  for (int cb = 0; cb < 5; cb++) {
    rx[cb] = *(const f4*)(rp + cb * 32);
    ry[cb] = *(const f4*)(rp + cb * 32 + 4);
  }
  // block's 512-row fbl slice -> LDS (128 float4; waves 0,1 issue 1 each)
  if (tid < 128) gload16f(fblb2 + rbase + tid * 4, S.fbl + tid * 4);
  // tiles 0..2
#pragma unroll
  for (int t = 0; t < 3; t++) {
    const float* s = fW + (rbase + (size_t)t * 32) * DR;
#pragma unroll
    for (int i = 0; i < 10; i++) {
      int f = tid + i * 256;
      gload16f(s + (size_t)f * 4, (float*)S.buf[t] + (size_t)f * 4);
    }
  }
  h8 bfr[5];
#pragma unroll
  for (int cb = 0; cb < 5; cb++) {
    h8 v;
    v[0] = (_Float16)rx[cb][0]; v[1] = (_Float16)rx[cb][1];
    v[2] = (_Float16)rx[cb][2]; v[3] = (_Float16)rx[cb][3];
    v[4] = (_Float16)ry[cb][0]; v[5] = (_Float16)ry[cb][1];
    v[6] = (_Float16)ry[cb][2]; v[7] = (_Float16)ry[cb][3];
    bfr[cb] = v;
  }
  // drain fbl+tile0; tiles 1,2 (20 loads) stay in flight
  asm volatile("s_waitcnt vmcnt(20) lgkmcnt(0)" ::: "memory");
  __builtin_amdgcn_s_barrier();
  __builtin_amdgcn_sched_barrier(0);

  const int rn = tid >> 4, rk = (tid >> 3) & 1, rcq = tid & 7;

  for (int j = 0; j < NT; j++) {
    const float* bp = (const float*)S.buf[j % 3];
    f4 acc = {0.f, 0.f, 0.f, 0.f};
    const float* arow = bp + (rt * 16 + l15) * DR + kh * 160 + lh * 8;
#pragma unroll
    for (int cb = 0; cb < 5; cb++) {
      f4 x = *(const f4*)(arow + cb * 32);
      f4 y = *(const f4*)(arow + cb * 32 + 4);
      h8 a;
      a[0] = (_Float16)x[0]; a[1] = (_Float16)x[1];
      a[2] = (_Float16)x[2]; a[3] = (_Float16)x[3];
      a[4] = (_Float16)y[0]; a[5] = (_Float16)y[1];
      a[6] = (_Float16)y[2]; a[7] = (_Float16)y[3];
      acc = __builtin_amdgcn_mfma_f32_16x16x32_f16(a, bfr[cb], acc, 0, 0, 0);
    }
#pragma unroll
    for (int rr = 0; rr < 4; rr++) S.csc[w][lh * 4 + rr][l15] = acc[rr];

    // B1: csc + buf-reads complete (LDS-only; DMA stays in flight)
    asm volatile("s_waitcnt lgkmcnt(0)" ::: "memory");
    __builtin_amdgcn_s_barrier();
    __builtin_amdgcn_sched_barrier(0);

    // repack: all 256 threads, exactly one 4-B store each
    {
      const unsigned g32 = (unsigned)(rbase + (size_t)j * 32);
      const unsigned G = g32 >> 15, o = (g32 >> 8) & 127u, c0 = (g32 & 255u) >> 1;
      h2 v2;
#pragma unroll
      for (int i = 0; i < 2; i++) {
        int rl32 = (rcq * 2 + i) * 2 + rk;
        int hp = (rl32 >> 4) * 2, rr2 = rl32 & 15;
        float s = S.csc[hp][rr2][rn] + S.csc[hp + 1][rr2][rn] + S.fbl[j * 32 + rl32];
        v2[i] = (_Float16)s;
      }
      unsigned q = 3u * (unsigned)rn + G;
      *(h2*)&wg[(((size_t)q * 128 + o) * 2 + rk) * 128 + c0 + rcq * 2] = v2;
    }
    __builtin_amdgcn_sched_barrier(0);   // pin: store issues before prefetch

    // prefetch tile j+3 into the buffer just retired
    if (j + 3 < NT) {
      float* dstb = (float*)S.buf[j % 3];
      const float* src = fW + (rbase + (size_t)(j + 3) * 32) * DR;
#pragma unroll
      for (int i = 0; i < 10; i++) {
        int f = tid + i * 256;
        gload16f(src + (size_t)f * 4, dstb + (size_t)f * 4);
      }
    }

    // B2: drain tile j+1 (20 newer prefetch loads stay in flight)
    if (j + 4 <= NT)
      asm volatile("s_waitcnt vmcnt(20) lgkmcnt(0)" ::: "memory");
    else if (j + 3 == NT)
      asm volatile("s_waitcnt vmcnt(10) lgkmcnt(0)" ::: "memory");
    else
      asm volatile("s_waitcnt vmcnt(0) lgkmcnt(0)" ::: "memory");
    __builtin_amdgcn_s_barrier();
    __builtin_amdgcn_sched_barrier(0);
  }
}

// ---------------------------------------------------------------------------
// pair body (verified r10/r12), on (tx, n). S.hin sized for max D (=4).
template <int D>
__device__ __forceinline__ void pair_body(SPair& S, int tx, int n, int tid,
                                          const _Float16* in, _Float16* out,
                                          const _Float16* w1p, const _Float16* w2p,
                                          const float* b1p, const float* b2p) {
  constexpr int HA = 16;
  constexpr int HI = HA + D;
  constexpr int RIN = 80 + D;
  static_assert(RIN * 128 <= sizeof(SPair::hin) / sizeof(_Float16), "hin size");
  _Float16* hin_l = S.hin;
  _Float16* a_l = S.a;
  const int t0 = tx * 64;
  const _Float16* inN = in + (size_t)n * (TLEN * CCH);

  if (tx == 0) {
    for (int f = tid; f < HI * 16; f += 256)
      *(int4*)(hin_l + (size_t)f * 8) = make_int4(0, 0, 0, 0);
    for (int f = HI * 16 + tid; f < RIN * 16; f += 256) {
      int p = f >> 4, l16 = f & 15;
      int c8 = (l16 ^ (p & 15)) << 3;
      gload16h(inN + (t0 - HI + p) * 128 + c8, hin_l + f * 8);
    }
  } else {
    for (int f = tid; f < RIN * 16; f += 256) {
      int p = f >> 4, l16 = f & 15;
      int c8 = (l16 ^ (p & 15)) << 3;
      gload16h(inN + (t0 - HI + p) * 128 + c8, hin_l + f * 8);
    }
  }
  __syncthreads();

  const int l = tid & 63, w = tid >> 6;
  const int l15 = l & 15, lh = l >> 4;
  const int o0 = w * 32;

  f4 acc1[2][5] = {};
#pragma unroll
  for (int tap = 0; tap < 2; tap++) {
#pragma unroll
    for (int cb = 0; cb < 4; cb++) {
      const int c0 = cb * 32 + lh * 8;
      h8 a[2], bfr[5];
#pragma unroll
      for (int i2 = 0; i2 < 2; i2++) {
        int o = o0 + i2 * 16 + l15;
        a[i2] = *(const h8*)&w1p[(o * 2 + tap) * 128 + c0];
      }
#pragma unroll
      for (int jt = 0; jt < 5; jt++) {
        int p = jt * 16 + l15 + tap * D;
        int cs = c0 ^ ((p & 15) << 3);
        bfr[jt] = *(const h8*)&hin_l[p * 128 + cs];
      }
#pragma unroll
      for (int i2 = 0; i2 < 2; i2++)
#pragma unroll
        for (int jt = 0; jt < 5; jt++)
          acc1[i2][jt] = __builtin_amdgcn_mfma_f32_16x16x32_f16(
              a[i2], bfr[jt], acc1[i2][jt], 0, 0, 0);
    }
  }
#pragma unroll
  for (int i2 = 0; i2 < 2; i2++) {
    f4 bv = *(const f4*)&b1p[o0 + i2 * 16 + lh * 4];
    const int base8 = o0 + i2 * 16 + (lh >> 1) * 8;
    const int sub = (lh & 1) * 4;
#pragma unroll
    for (int jt = 0; jt < 5; jt++) {
      int p = jt * 16 + l15;
      h4 sv;
      if (tx == 0 && jt == 0) {
        sv[0] = sv[1] = sv[2] = sv[3] = (_Float16)0.f;
      } else {
        f4 v = acc1[i2][jt];
#pragma unroll
        for (int rr = 0; rr < 4; rr++) sv[rr] = (_Float16)fmaxf(v[rr] + bv[rr], 0.f);
      }
      *(h4*)&a_l[p * 128 + (base8 ^ ((p & 15) << 3)) + sub] = sv;
    }
  }
  __syncthreads();

  f4 acc2[2][4] = {};
#pragma unroll
  for (int tap = 0; tap < 2; tap++) {
#pragma unroll
    for (int cb = 0; cb < 4; cb++) {
      const int c0 = cb * 32 + lh * 8;
      h8 a[2], bfr[4];
#pragma unroll
      for (int i2 = 0; i2 < 2; i2++) {
        int o = o0 + i2 * 16 + l15;
        a[i2] = *(const h8*)&w2p[(o * 2 + tap) * 128 + c0];
      }
#pragma unroll
      for (int jt = 0; jt < 4; jt++) {
        int pa = jt * 16 + l15 + (HA - D) + tap * D;
        int cs = c0 ^ ((pa & 15) << 3);
        bfr[jt] = *(const h8*)&a_l[pa * 128 + cs];
      }
#pragma unroll
      for (int i2 = 0; i2 < 2; i2++)
#pragma unroll
        for (int jt = 0; jt < 4; jt++)
          acc2[i2][jt] = __builtin_amdgcn_mfma_f32_16x16x32_f16(
              a[i2], bfr[jt], acc2[i2][jt], 0, 0, 0);
    }
  }

  _Float16* outN = out + (size_t)n * (TLEN * CCH);
#pragma unroll
  for (int i2 = 0; i2 < 2; i2++) {
    f4 bv = *(const f4*)&b2p[o0 + i2 * 16 + lh * 4];
    const int base8 = o0 + i2 * 16 + (lh >> 1) * 8;
    const int sub = (lh & 1) * 4;
#pragma unroll
    for (int jt = 0; jt < 4; jt++) {
      int t = t0 + jt * 16 + l15;
      int pr = jt * 16 + l15 + HA + D;
      h4 rv = *(const h4*)&hin_l[pr * 128 + (base8 ^ ((pr & 15) << 3)) + sub];
      f4 v = acc2[i2][jt];
      h4 sv;
#pragma unroll
      for (int rr = 0; rr < 4; rr++) {
        float z = fmaxf(v[rr] + bv[rr], 0.f);
        sv[rr] = (_Float16)fmaxf(z + (float)rv[rr], 0.f);
      }
      *(h4*)&outN[t * 128 + o0 + i2 * 16 + lh * 4] = sv;
    }
  }
}

// ---------------------------------------------------------------------------
// Fused gen || pair1: blocks 0..191 gen, 192..447 pair<1>. No cross-role deps.
__global__ __launch_bounds__(256, 1) void k_genpair(
    const float* __restrict__ r, const float* __restrict__ fW,
    const float* __restrict__ fblb2, _Float16* __restrict__ wg,
    const _Float16* __restrict__ h0, _Float16* __restrict__ h1,
    const _Float16* __restrict__ Wsh,
    const float* __restrict__ b1, const float* __restrict__ b2) {
  __shared__ SU su;
  const int bid = blockIdx.x, tid = threadIdx.x;
  if (bid < 192) {
    gen_body(su.g, bid, tid, r, fW, fblb2, wg);
  } else {
    int q = bid - 192;
    pair_body<1>(su.p, q & 15, q >> 4, tid, h0, h1,
                 Wsh, Wsh + 3 * 32768, b1, b2);
  }
}

// ---------------------------------------------------------------------------
// Standalone pair kernel (verified r10/r12), D = 2, 4.
template <int D>
__global__ __launch_bounds__(256) void k_pair(const _Float16* __restrict__ in,
                                              _Float16* __restrict__ out,
                                              const _Float16* __restrict__ w1p,
                                              const _Float16* __restrict__ w2p,
                                              const float* __restrict__ b1p,
                                              const float* __restrict__ b2p) {
  __shared__ SPair sp;
  pair_body<D>(sp, blockIdx.x, blockIdx.y, threadIdx.x, in, out, w1p, w2p,
               b1p, b2p);
}

// ---------------------------------------------------------------------------
// Group conv (verified r10/r12), res from hl.
template <int D>   // 8, 16
__global__ __launch_bounds__(256) void k_gconv(const _Float16* __restrict__ in,
                                               _Float16* __restrict__ out,
                                               const _Float16* __restrict__ wBase) {
  __shared__ _Float16 Wl[256 * 128];
  __shared__ _Float16 hl[(64 + D) * 128];
  const int tid = threadIdx.x;
  const int n = blockIdx.y, t0 = blockIdx.x * 64;
  const _Float16* inN = in + (size_t)n * (TLEN * CCH);
  const _Float16* wp = wBase + (size_t)n * 32768;

  for (int f = tid; f < 4096; f += 256) {
    int row = f >> 4, l16 = f & 15;
    int c8 = (l16 ^ ((row >> 1) & 15)) << 3;
    gload16h(wp + row * 128 + c8, Wl + f * 8);
  }
  if (blockIdx.x == 0) {
    for (int f = tid; f < D * 16; f += 256)
      *(int4*)(hl + (size_t)f * 8) = make_int4(0, 0, 0, 0);
    for (int f = D * 16 + tid; f < (64 + D) * 16; f += 256) {
      int p = f >> 4, l16 = f & 15;
      int c8 = (l16 ^ (p & 15)) << 3;
      gload16h(inN + (t0 - D + p) * 128 + c8, hl + f * 8);
    }
  } else {
    for (int f = tid; f < (64 + D) * 16; f += 256) {
      int p = f >> 4, l16 = f & 15;
      int c8 = (l16 ^ (p & 15)) << 3;
      gload16h(inN + (t0 - D + p) * 128 + c8, hl + f * 8);
    }
  }
  __syncthreads();

  const int l = tid & 63, w = tid >> 6;
  const int l15 = l & 15, lh = l >> 4;
  const int o0 = w * 32;
  f4 acc[2][4] = {};

#pragma unroll
  for (int tap = 0; tap < 2; tap++) {
#pragma unroll
    for (int cb = 0; cb < 4; cb++) {
      const int c0 = cb * 32 + 8 * lh;
      h8 a[2], bfr[4];
#pragma unroll
      for (int i2 = 0; i2 < 2; i2++) {
        int o = o0 + i2 * 16 + l15;
        int cs = c0 ^ ((o & 15) << 3);
        a[i2] = *(const h8*)&Wl[(o * 2 + tap) * 128 + cs];
      }
#pragma unroll
      for (int jt = 0; jt < 4; jt++) {
        int p = jt * 16 + l15 + tap * D;
        int cs = c0 ^ ((p & 15) << 3);
        bfr[jt] = *(const h8*)&hl[p * 128 + cs];
      }
#pragma unroll
      for (int i2 = 0; i2 < 2; i2++)
#pragma unroll
        for (int jt = 0; jt < 4; jt++)
          acc[i2][jt] = __builtin_amdgcn_mfma_f32_16x16x32_f16(
              a[i2], bfr[jt], acc[i2][jt], 0, 0, 0);
    }
  }

  _Float16* outN = out + (size_t)n * (TLEN * CCH);
#pragma unroll
  for (int i2 = 0; i2 < 2; i2++) {
    const int base8 = o0 + i2 * 16 + (lh >> 1) * 8;
    const int sub = (lh & 1) * 4;
#pragma unroll
    for (int jt = 0; jt < 4; jt++) {
      int t = t0 + jt * 16 + l15;
      int pr = jt * 16 + l15 + D;
      h4 rv = *(const h4*)&hl[pr * 128 + (base8 ^ ((pr & 15) << 3)) + sub];
      f4 v = acc[i2][jt];
      h4 sv;
#pragma unroll
      for (int rr = 0; rr < 4; rr++) {
        float z = fmaxf(v[rr], 0.f);
        sv[rr] = (_Float16)fmaxf(z + (float)rv[rr], 0.f);
      }
      *(h4*)&outN[t * 128 + o0 + i2 * 16 + lh * 4] = sv;
    }
  }
}

// ---------------------------------------------------------------------------
// Fused group conv D=32 + final linear (verified r10/r12).
__global__ __launch_bounds__(256) void k_glin(const _Float16* __restrict__ in,
                                              float* __restrict__ outp,
                                              const _Float16* __restrict__ wBase,
                                              const _Float16* __restrict__ linWh,
                                              const float* __restrict__ lbias) {
  constexpr int D = 32;
  __shared__ _Float16 Wl[256 * 128];
  __shared__ _Float16 hl[(64 + D) * 128];
  __shared__ _Float16 a_l[64 * 128];
  const int tid = threadIdx.x;
  const int n = blockIdx.y, t0 = blockIdx.x * 64;
  const _Float16* inN = in + (size_t)n * (TLEN * CCH);
  const _Float16* wp = wBase + (size_t)n * 32768;

  for (int f = tid; f < 4096; f += 256) {
    int row = f >> 4, l16 = f & 15;
    int c8 = (l16 ^ ((row >> 1) & 15)) << 3;
    gload16h(wp + row * 128 + c8, Wl + f * 8);
  }
  if (blockIdx.x == 0) {
    for (int f = tid; f < D * 16; f += 256)
      *(int4*)(hl + (size_t)f * 8) = make_int4(0, 0, 0, 0);
    for (int f = D * 16 + tid; f < (64 + D) * 16; f += 256) {
      int p = f >> 4, l16 = f & 15;
      int c8 = (l16 ^ (p & 15)) << 3;
      gload16h(inN + (t0 - D + p) * 128 + c8, hl + f * 8);
    }
  } else {
    for (int f = tid; f < (64 + D) * 16; f += 256) {
      int p = f >> 4, l16 = f & 15;
      int c8 = (l16 ^ (p & 15)) << 3;
      gload16h(inN + (t0 - D + p) * 128 + c8, hl + f * 8);
    }
  }
  __syncthreads();

  const int l = tid & 63, w = tid >> 6;
  const int l15 = l & 15, lh = l >> 4;
  const int o0 = w * 32;
  f4 acc[2][4] = {};

#pragma unroll
  for (int tap = 0; tap < 2; tap++) {
#pragma unroll
    for (int cb = 0; cb < 4; cb++) {
      const int c0 = cb * 32 + 8 * lh;
      h8 a[2], bfr[4];
#pragma unroll
      for (int i2 = 0; i2 < 2; i2++) {
        int o = o0 + i2 * 16 + l15;
        int cs = c0 ^ ((o & 15) << 3);
        a[i2] = *(const h8*)&Wl[(o * 2 + tap) * 128 + cs];
      }
#pragma unroll
      for (int jt = 0; jt < 4; jt++) {
        int p = jt * 16 + l15 + tap * D;
        int cs = c0 ^ ((p & 15) << 3);
        bfr[jt] = *(const h8*)&hl[p * 128 + cs];
      }
#pragma unroll
      for (int i2 = 0; i2 < 2; i2++)
#pragma unroll
        for (int jt = 0; jt < 4; jt++)
          acc[i2][jt] = __builtin_amdgcn_mfma_f32_16x16x32_f16(
              a[i2], bfr[jt], acc[i2][jt], 0, 0, 0);
    }
  }

#pragma unroll
  for (int i2 = 0; i2 < 2; i2++) {
    const int base8 = o0 + i2 * 16 + (lh >> 1) * 8;
    const int sub = (lh & 1) * 4;
#pragma unroll
    for (int jt = 0; jt < 4; jt++) {
      int p = jt * 16 + l15;
      int pr = p + D;
      h4 rv = *(const h4*)&hl[pr * 128 + (base8 ^ ((pr & 15) << 3)) + sub];
      f4 v = acc[i2][jt];
      h4 sv;
#pragma unroll
      for (int rr = 0; rr < 4; rr++) {
        float z = fmaxf(v[rr], 0.f);
        sv[rr] = (_Float16)fmaxf(z + (float)rv[rr], 0.f);
      }
      *(h4*)&a_l[p * 128 + (base8 ^ (l15 << 3)) + sub] = sv;
    }
  }
  __syncthreads();

  f4 acc3[2][4] = {};
#pragma unroll
  for (int cb = 0; cb < 4; cb++) {
    const int c0 = cb * 32 + lh * 8;
    h8 a[2], bfr[4];
#pragma unroll
    for (int i2 = 0; i2 < 2; i2++) {
      int o = o0 + i2 * 16 + l15;
      a[i2] = *(const h8*)&linWh[o * 128 + c0];
    }
#pragma unroll
    for (int jt = 0; jt < 4; jt++) {
      int p = jt * 16 + l15;
      int cs = c0 ^ ((p & 15) << 3);
      bfr[jt] = *(const h8*)&a_l[p * 128 + cs];
    }
#pragma unroll
    for (int i2 = 0; i2 < 2; i2++)
#pragma unroll
      for (int jt = 0; jt < 4; jt++)
        acc3[i2][jt] = __builtin_amdgcn_mfma_f32_16x16x32_f16(
            a[i2], bfr[jt], acc3[i2][jt], 0, 0, 0);
  }

#pragma unroll
  for (int i2 = 0; i2 < 2; i2++) {
    int o = o0 + i2 * 16 + lh * 4;
    f4 bv = *(const f4*)&lbias[o];
#pragma unroll
    for (int jt = 0; jt < 4; jt++) {
      int t = t0 + jt * 16 + l15;
      f4 v = acc3[i2][jt];
      float4 sv = make_float4(v[0] + bv[0], v[1] + bv[1], v[2] + bv[2], v[3] + bv[3]);
      *(float4*)&outp[((size_t)n * TLEN + t) * CCH + o] = sv;
    }
  }
}

// ---------------------------------------------------------------------------
extern "C" void kernel_launch(void* const* d_in, const int* in_sizes, int n_in,
                              void* d_out, int out_size, void* d_ws, size_t ws_size,
                              hipStream_t stream) {
  const float* x  = (const float*)d_in[0];
  const float* r  = (const float*)d_in[1];
  // d_in[2] = f_out_same_in_size (==1)
  const float* w1 = (const float*)d_in[3];
  const float* b1 = (const float*)d_in[4];
  const float* w2 = (const float*)d_in[5];
  const float* b2 = (const float*)d_in[6];
  const float* fW = (const float*)d_in[7];
  const float* fb = (const float*)d_in[8];
  const float* lb = (const float*)d_in[9];
  const float* lw = (const float*)d_in[10];
  const float* lbias = (const float*)d_in[11];
  float* out = (float*)d_out;

  _Float16* h0    = (_Float16*)d_ws;        // 2,097,152 halves
  _Float16* h1    = h0 + 2097152;           // 2,097,152
  _Float16* Wsh   = h1 + 2097152;           // 393,216
  _Float16* linWh = Wsh + 393216;           // 16,384
  _Float16* Wg    = linWh + 16384;          // 1,572,864
  float*    fblb2 = (float*)(Wg + 1572864); // 98,304 floats

  k_init<<<1024, 256, 0, stream>>>(x, w1, w2, lw, fb, lb, h0, Wsh, linWh, fblb2);
  // gen (blocks 0..191) || pair1 (blocks 192..447)
  k_genpair<<<448, 256, 0, stream>>>(r, fW, fblb2, Wg, h0, h1, Wsh, b1, b2);

  const dim3 cg(16, 16);
  k_pair<2><<<cg, 256, 0, stream>>>(h1, h0, Wsh + 1 * 32768, Wsh + 4 * 32768,
                                    b1 + 128, b2 + 128);
  k_pair<4><<<cg, 256, 0, stream>>>(h0, h1, Wsh + 2 * 32768, Wsh + 5 * 32768,
                                    b1 + 256, b2 + 256);
  k_gconv<8> <<<cg, 256, 0, stream>>>(h1, h0, Wg);
  k_gconv<16><<<cg, 256, 0, stream>>>(h0, h1, Wg + 524288);
  k_glin<<<cg, 256, 0, stream>>>(h1, out, Wg + 1048576, linWh, lbias);
}

// Round 15
// 75.337 us; speedup vs baseline: 1.0968x; 1.0359x over previous
//
#include <hip/hip_runtime.h>

// Problem constants
#define NB    16
#define TLEN  1024
#define CCH   128
#define DR    320

typedef _Float16 h8 __attribute__((ext_vector_type(8)));
typedef _Float16 h4 __attribute__((ext_vector_type(4)));
typedef _Float16 h2 __attribute__((ext_vector_type(2)));
typedef float    f4 __attribute__((ext_vector_type(4)));

// async global->LDS, 16 B/lane. LDS dest = readfirstlane(base)+lane*16, LINEAR.
__device__ __forceinline__ void gload16h(const _Float16* g, _Float16* l) {
  __builtin_amdgcn_global_load_lds(
      (const __attribute__((address_space(1))) void*)g,
      (__attribute__((address_space(3))) void*)l, 16, 0, 0);
}
__device__ __forceinline__ void gload16f(const float* g, float* l) {
  __builtin_amdgcn_global_load_lds(
      (const __attribute__((address_space(1))) void*)g,
      (__attribute__((address_space(3))) void*)l, 16, 0, 0);
}

// ---------------------------------------------------------------------------
// Init: cast x->h0 (f16), weight prep, fblb2 = fb+lb. 1024 blocks. (verified)
__global__ __launch_bounds__(256) void k_init(const float* __restrict__ x,
                                              const float* __restrict__ w1,
                                              const float* __restrict__ w2,
                                              const float* __restrict__ linw,
                                              const float* __restrict__ fb,
                                              const float* __restrict__ lb,
                                              _Float16* __restrict__ h0,
                                              _Float16* __restrict__ Wsh,
                                              _Float16* __restrict__ linWh,
                                              float* __restrict__ fblb2) {
  int i = blockIdx.x * 256 + threadIdx.x;     // 0..262143
  const float4* src = (const float4*)x + (size_t)i * 2;
  float4 a = src[0], b = src[1];
  h8 v;
  v[0] = (_Float16)a.x; v[1] = (_Float16)a.y; v[2] = (_Float16)a.z; v[3] = (_Float16)a.w;
  v[4] = (_Float16)b.x; v[5] = (_Float16)b.y; v[6] = (_Float16)b.z; v[7] = (_Float16)b.w;
  *(h8*)(h0 + (size_t)i * 8) = v;

  if (i < 6 * 32768) {
    int c = i & 127, k = (i >> 7) & 1, o = (i >> 8) & 127, i3 = i >> 15;
    const float* srcw = (i3 < 3) ? (w1 + i3 * 32768) : (w2 + (i3 - 3) * 32768);
    Wsh[i] = (_Float16)srcw[(o * 128 + c) * 2 + k];
  }
  if (i < 16384) linWh[i] = (_Float16)linw[i];
  if (i < 98304) fblb2[i] = fb[i] + lb[i];
}

// ---------------------------------------------------------------------------
// Shared structs for the fused gen||pair1 kernel
struct SGen {
  float buf[3][32 * DR];    // 122,880 B
  float csc[4][16][16];     // 4,096 B
  float fbl[512];           // 2,048 B   (total 129,024 B)
};
struct SPair {              // sized for the LARGEST D used (D=4: RIN=84)
  _Float16 hin[84 * 128];
  _Float16 a[80 * 128];
};
union alignas(16) SU { SGen g; SPair p; };

// ---------------------------------------------------------------------------
// gen body (verified r14): 192 blocks x 512 rows, 16 tiles; 3-buffer pipeline.
__device__ __forceinline__ void gen_body(SGen& S, int bid, int tid,
                                         const float* __restrict__ r,
                                         const float* __restrict__ fW,
                                         const float* __restrict__ fblb2,
                                         _Float16* __restrict__ wg) {
  constexpr int NT = 16;
  const size_t rbase = (size_t)bid * 512;

  const int l = tid & 63, w = tid >> 6;
  const int l15 = l & 15, lh = l >> 4;
  const int rt = w >> 1, kh = w & 1;

  f4 rx[5], ry[5];
  const float* rp = r + l15 * DR + kh * 160 + lh * 8;
#pragma unroll
  for (int cb = 0; cb < 5; cb++) {
    rx[cb] = *(const f4*)(rp + cb * 32);
    ry[cb] = *(const f4*)(rp + cb * 32 + 4);
  }
  if (tid < 128) gload16f(fblb2 + rbase + tid * 4, S.fbl + tid * 4);
#pragma unroll
  for (int t = 0; t < 3; t++) {
    const float* s = fW + (rbase + (size_t)t * 32) * DR;
#pragma unroll
    for (int i = 0; i < 10; i++) {
      int f = tid + i * 256;
      gload16f(s + (size_t)f * 4, (float*)S.buf[t] + (size_t)f * 4);
    }
  }
  h8 bfr[5];
#pragma unroll
  for (int cb = 0; cb < 5; cb++) {
    h8 v;
    v[0] = (_Float16)rx[cb][0]; v[1] = (_Float16)rx[cb][1];
    v[2] = (_Float16)rx[cb][2]; v[3] = (_Float16)rx[cb][3];
    v[4] = (_Float16)ry[cb][0]; v[5] = (_Float16)ry[cb][1];
    v[6] = (_Float16)ry[cb][2]; v[7] = (_Float16)ry[cb][3];
    bfr[cb] = v;
  }
  asm volatile("s_waitcnt vmcnt(20) lgkmcnt(0)" ::: "memory");
  __builtin_amdgcn_s_barrier();
  __builtin_amdgcn_sched_barrier(0);

  const int rn = tid >> 4, rk = (tid >> 3) & 1, rcq = tid & 7;

  for (int j = 0; j < NT; j++) {
    const float* bp = (const float*)S.buf[j % 3];
    f4 acc = {0.f, 0.f, 0.f, 0.f};
    const float* arow = bp + (rt * 16 + l15) * DR + kh * 160 + lh * 8;
#pragma unroll
    for (int cb = 0; cb < 5; cb++) {
      f4 x = *(const f4*)(arow + cb * 32);
      f4 y = *(const f4*)(arow + cb * 32 + 4);
      h8 a;
      a[0] = (_Float16)x[0]; a[1] = (_Float16)x[1];
      a[2] = (_Float16)x[2]; a[3] = (_Float16)x[3];
      a[4] = (_Float16)y[0]; a[5] = (_Float16)y[1];
      a[6] = (_Float16)y[2]; a[7] = (_Float16)y[3];
      acc = __builtin_amdgcn_mfma_f32_16x16x32_f16(a, bfr[cb], acc, 0, 0, 0);
    }
#pragma unroll
    for (int rr = 0; rr < 4; rr++) S.csc[w][lh * 4 + rr][l15] = acc[rr];

    asm volatile("s_waitcnt lgkmcnt(0)" ::: "memory");
    __builtin_amdgcn_s_barrier();
    __builtin_amdgcn_sched_barrier(0);

    {
      const unsigned g32 = (unsigned)(rbase + (size_t)j * 32);
      const unsigned G = g32 >> 15, o = (g32 >> 8) & 127u, c0 = (g32 & 255u) >> 1;
      h2 v2;
#pragma unroll
      for (int i = 0; i < 2; i++) {
        int rl32 = (rcq * 2 + i) * 2 + rk;
        int hp = (rl32 >> 4) * 2, rr2 = rl32 & 15;
        float s = S.csc[hp][rr2][rn] + S.csc[hp + 1][rr2][rn] + S.fbl[j * 32 + rl32];
        v2[i] = (_Float16)s;
      }
      unsigned q = 3u * (unsigned)rn + G;
      *(h2*)&wg[(((size_t)q * 128 + o) * 2 + rk) * 128 + c0 + rcq * 2] = v2;
    }
    __builtin_amdgcn_sched_barrier(0);

    if (j + 3 < NT) {
      float* dstb = (float*)S.buf[j % 3];
      const float* src = fW + (rbase + (size_t)(j + 3) * 32) * DR;
#pragma unroll
      for (int i = 0; i < 10; i++) {
        int f = tid + i * 256;
        gload16f(src + (size_t)f * 4, dstb + (size_t)f * 4);
      }
    }

    if (j + 4 <= NT)
      asm volatile("s_waitcnt vmcnt(20) lgkmcnt(0)" ::: "memory");
    else if (j + 3 == NT)
      asm volatile("s_waitcnt vmcnt(10) lgkmcnt(0)" ::: "memory");
    else
      asm volatile("s_waitcnt vmcnt(0) lgkmcnt(0)" ::: "memory");
    __builtin_amdgcn_s_barrier();
    __builtin_amdgcn_sched_barrier(0);
  }
}

// ---------------------------------------------------------------------------
// pair body (verified r14), on (tx, n). S.hin sized for max D (=4).
template <int D>
__device__ __forceinline__ void pair_body(SPair& S, int tx, int n, int tid,
                                          const _Float16* in, _Float16* out,
                                          const _Float16* w1p, const _Float16* w2p,
                                          const float* b1p, const float* b2p) {
  constexpr int HA = 16;
  constexpr int HI = HA + D;
  constexpr int RIN = 80 + D;
  static_assert(RIN * 128 <= sizeof(SPair::hin) / sizeof(_Float16), "hin size");
  _Float16* hin_l = S.hin;
  _Float16* a_l = S.a;
  const int t0 = tx * 64;
  const _Float16* inN = in + (size_t)n * (TLEN * CCH);

  if (tx == 0) {
    for (int f = tid; f < HI * 16; f += 256)
      *(int4*)(hin_l + (size_t)f * 8) = make_int4(0, 0, 0, 0);
    for (int f = HI * 16 + tid; f < RIN * 16; f += 256) {
      int p = f >> 4, l16 = f & 15;
      int c8 = (l16 ^ (p & 15)) << 3;
      gload16h(inN + (t0 - HI + p) * 128 + c8, hin_l + f * 8);
    }
  } else {
    for (int f = tid; f < RIN * 16; f += 256) {
      int p = f >> 4, l16 = f & 15;
      int c8 = (l16 ^ (p & 15)) << 3;
      gload16h(inN + (t0 - HI + p) * 128 + c8, hin_l + f * 8);
    }
  }
  __syncthreads();

  const int l = tid & 63, w = tid >> 6;
  const int l15 = l & 15, lh = l >> 4;
  const int o0 = w * 32;

  f4 acc1[2][5] = {};
#pragma unroll
  for (int tap = 0; tap < 2; tap++) {
#pragma unroll
    for (int cb = 0; cb < 4; cb++) {
      const int c0 = cb * 32 + lh * 8;
      h8 a[2], bfr[5];
#pragma unroll
      for (int i2 = 0; i2 < 2; i2++) {
        int o = o0 + i2 * 16 + l15;
        a[i2] = *(const h8*)&w1p[(o * 2 + tap) * 128 + c0];
      }
#pragma unroll
      for (int jt = 0; jt < 5; jt++) {
        int p = jt * 16 + l15 + tap * D;
        int cs = c0 ^ ((p & 15) << 3);
        bfr[jt] = *(const h8*)&hin_l[p * 128 + cs];
      }
#pragma unroll
      for (int i2 = 0; i2 < 2; i2++)
#pragma unroll
        for (int jt = 0; jt < 5; jt++)
          acc1[i2][jt] = __builtin_amdgcn_mfma_f32_16x16x32_f16(
              a[i2], bfr[jt], acc1[i2][jt], 0, 0, 0);
    }
  }
#pragma unroll
  for (int i2 = 0; i2 < 2; i2++) {
    f4 bv = *(const f4*)&b1p[o0 + i2 * 16 + lh * 4];
    const int base8 = o0 + i2 * 16 + (lh >> 1) * 8;
    const int sub = (lh & 1) * 4;
#pragma unroll
    for (int jt = 0; jt < 5; jt++) {
      int p = jt * 16 + l15;
      h4 sv;
      if (tx == 0 && jt == 0) {
        sv[0] = sv[1] = sv[2] = sv[3] = (_Float16)0.f;
      } else {
        f4 v = acc1[i2][jt];
#pragma unroll
        for (int rr = 0; rr < 4; rr++) sv[rr] = (_Float16)fmaxf(v[rr] + bv[rr], 0.f);
      }
      *(h4*)&a_l[p * 128 + (base8 ^ ((p & 15) << 3)) + sub] = sv;
    }
  }
  __syncthreads();

  f4 acc2[2][4] = {};
#pragma unroll
  for (int tap = 0; tap < 2; tap++) {
#pragma unroll
    for (int cb = 0; cb < 4; cb++) {
      const int c0 = cb * 32 + lh * 8;
      h8 a[2], bfr[4];
#pragma unroll
      for (int i2 = 0; i2 < 2; i2++) {
        int o = o0 + i2 * 16 + l15;
        a[i2] = *(const h8*)&w2p[(o * 2 + tap) * 128 + c0];
      }
#pragma unroll
      for (int jt = 0; jt < 4; jt++) {
        int pa = jt * 16 + l15 + (HA - D) + tap * D;
        int cs = c0 ^ ((pa & 15) << 3);
        bfr[jt] = *(const h8*)&a_l[pa * 128 + cs];
      }
#pragma unroll
      for (int i2 = 0; i2 < 2; i2++)
#pragma unroll
        for (int jt = 0; jt < 4; jt++)
          acc2[i2][jt] = __builtin_amdgcn_mfma_f32_16x16x32_f16(
              a[i2], bfr[jt], acc2[i2][jt], 0, 0, 0);
    }
  }

  _Float16* outN = out + (size_t)n * (TLEN * CCH);
#pragma unroll
  for (int i2 = 0; i2 < 2; i2++) {
    f4 bv = *(const f4*)&b2p[o0 + i2 * 16 + lh * 4];
    const int base8 = o0 + i2 * 16 + (lh >> 1) * 8;
    const int sub = (lh & 1) * 4;
#pragma unroll
    for (int jt = 0; jt < 4; jt++) {
      int t = t0 + jt * 16 + l15;
      int pr = jt * 16 + l15 + HA + D;
      h4 rv = *(const h4*)&hin_l[pr * 128 + (base8 ^ ((pr & 15) << 3)) + sub];
      f4 v = acc2[i2][jt];
      h4 sv;
#pragma unroll
      for (int rr = 0; rr < 4; rr++) {
        float z = fmaxf(v[rr] + bv[rr], 0.f);
        sv[rr] = (_Float16)fmaxf(z + (float)rv[rr], 0.f);
      }
      *(h4*)&outN[t * 128 + o0 + i2 * 16 + lh * 4] = sv;
    }
  }
}

// ---------------------------------------------------------------------------
// Fused gen || pair1 (verified r14).
__global__ __launch_bounds__(256, 1) void k_genpair(
    const float* __restrict__ r, const float* __restrict__ fW,
    const float* __restrict__ fblb2, _Float16* __restrict__ wg,
    const _Float16* __restrict__ h0, _Float16* __restrict__ h1,
    const _Float16* __restrict__ Wsh,
    const float* __restrict__ b1, const float* __restrict__ b2) {
  __shared__ SU su;
  const int bid = blockIdx.x, tid = threadIdx.x;
  if (bid < 192) {
    gen_body(su.g, bid, tid, r, fW, fblb2, wg);
  } else {
    int q = bid - 192;
    pair_body<1>(su.p, q & 15, q >> 4, tid, h0, h1,
                 Wsh, Wsh + 3 * 32768, b1, b2);
  }
}

// ---------------------------------------------------------------------------
// Standalone pair kernel (verified), D = 2, 4.
template <int D>
__global__ __launch_bounds__(256) void k_pair(const _Float16* __restrict__ in,
                                              _Float16* __restrict__ out,
                                              const _Float16* __restrict__ w1p,
                                              const _Float16* __restrict__ w2p,
                                              const float* __restrict__ b1p,
                                              const float* __restrict__ b2p) {
  __shared__ SPair sp;
  pair_body<D>(sp, blockIdx.x, blockIdx.y, threadIdx.x, in, out, w1p, w2p,
               b1p, b2p);
}

// ---------------------------------------------------------------------------
// One group-conv stage on LDS buffers (generalized verified gconv body):
// out rows r in [0, NJ*16), out_t_base = in_t_base + D (p_in = r + tap*D);
// out = relu(relu(conv(in)) + in[r+D]); rows r < zlim stored as ZERO.
template <int D, int NJ>
__device__ __forceinline__ void gstage(const _Float16* __restrict__ Wl,
                                       const _Float16* __restrict__ inb,
                                       _Float16* __restrict__ outb,
                                       int zlim, int tid) {
  const int l = tid & 63, w = tid >> 6;
  const int l15 = l & 15, lh = l >> 4;
  const int o0 = w * 32;
  f4 acc[2][NJ] = {};

#pragma unroll
  for (int tap = 0; tap < 2; tap++) {
#pragma unroll
    for (int cb = 0; cb < 4; cb++) {
      const int c0 = cb * 32 + 8 * lh;
      h8 a[2], bfr[NJ];
#pragma unroll
      for (int i2 = 0; i2 < 2; i2++) {
        int o = o0 + i2 * 16 + l15;
        int cs = c0 ^ ((o & 15) << 3);
        a[i2] = *(const h8*)&Wl[(o * 2 + tap) * 128 + cs];
      }
#pragma unroll
      for (int jt = 0; jt < NJ; jt++) {
        int p = jt * 16 + l15 + tap * D;
        int cs = c0 ^ ((p & 15) << 3);
        bfr[jt] = *(const h8*)&inb[p * 128 + cs];
      }
#pragma unroll
      for (int i2 = 0; i2 < 2; i2++)
#pragma unroll
        for (int jt = 0; jt < NJ; jt++)
          acc[i2][jt] = __builtin_amdgcn_mfma_f32_16x16x32_f16(
              a[i2], bfr[jt], acc[i2][jt], 0, 0, 0);
    }
  }

#pragma unroll
  for (int i2 = 0; i2 < 2; i2++) {
    const int base8 = o0 + i2 * 16 + (lh >> 1) * 8;
    const int sub = (lh & 1) * 4;
#pragma unroll
    for (int jt = 0; jt < NJ; jt++) {
      int rrow = jt * 16 + l15;
      int pr = rrow + D;
      h4 sv;
      if (rrow < zlim) {
        sv[0] = sv[1] = sv[2] = sv[3] = (_Float16)0.f;
      } else {
        h4 rv = *(const h4*)&inb[pr * 128 + (base8 ^ ((pr & 15) << 3)) + sub];
        f4 v = acc[i2][jt];
#pragma unroll
        for (int rr = 0; rr < 4; rr++) {
          float z = fmaxf(v[rr], 0.f);
          sv[rr] = (_Float16)fmaxf(z + (float)rv[rr], 0.f);
        }
      }
      *(h4*)&outb[rrow * 128 + (base8 ^ (l15 << 3)) + sub] = sv;
    }
  }
}

// ---------------------------------------------------------------------------
// Fused group chain: conv8 -> conv16 -> conv32 -> linear, intermediates in LDS.
// in = pair4 output. Per block (tx, n): stage in rows [t0-56, t0+64) (120),
// out1 [t0-48,+64) (112, bufB), out2 [t0-32,+64) (96, bufA reuse),
// conv32+res -> a_l (bufB reuse), linear -> out.
__global__ __launch_bounds__(256, 1) void k_group(const _Float16* __restrict__ in,
                                                  float* __restrict__ outp,
                                                  const _Float16* __restrict__ wg,
                                                  const _Float16* __restrict__ linWh,
                                                  const float* __restrict__ lbias) {
  __shared__ _Float16 bufA[120 * 128];   // 30 KB: in1, then out2
  __shared__ _Float16 bufB[112 * 128];   // 28 KB: out1, then a_l
  __shared__ _Float16 Wl[256 * 128];     // 64 KB, reloaded per stage
  const int tid = threadIdx.x;
  const int tx = blockIdx.x, n = blockIdx.y;
  const int t0 = tx * 64;
  const _Float16* inN = in + (size_t)n * (TLEN * CCH);
  const _Float16* wp1 = wg + (size_t)n * 32768;             // stage1 (i=0)
  const _Float16* wp2 = wg + 524288 + (size_t)n * 32768;    // stage2 (i=1)
  const _Float16* wp3 = wg + 1048576 + (size_t)n * 32768;   // stage3 (i=2)

  // stage in1: rows p -> t = t0 - 56 + p, p in [0,120)
  if (tx == 0) {
    for (int f = tid; f < 56 * 16; f += 256)
      *(int4*)(bufA + (size_t)f * 8) = make_int4(0, 0, 0, 0);
    for (int f = 56 * 16 + tid; f < 120 * 16; f += 256) {
      int p = f >> 4, l16 = f & 15;
      int c8 = (l16 ^ (p & 15)) << 3;
      gload16h(inN + (t0 - 56 + p) * 128 + c8, bufA + f * 8);
    }
  } else {
    for (int f = tid; f < 120 * 16; f += 256) {
      int p = f >> 4, l16 = f & 15;
      int c8 = (l16 ^ (p & 15)) << 3;
      gload16h(inN + (t0 - 56 + p) * 128 + c8, bufA + f * 8);
    }
  }
  // stage1 weights
  for (int f = tid; f < 4096; f += 256) {
    int row = f >> 4, l16 = f & 15;
    int c8 = (l16 ^ ((row >> 1) & 15)) << 3;
    gload16h(wp1 + row * 128 + c8, Wl + f * 8);
  }
  __syncthreads();

  // stage1: conv8, out1 rows [t0-48, +64): 7 tiles, bufA -> bufB
  gstage<8, 7>(Wl, bufA, bufB, (tx == 0) ? 48 : 0, tid);
  __syncthreads();
  for (int f = tid; f < 4096; f += 256) {
    int row = f >> 4, l16 = f & 15;
    int c8 = (l16 ^ ((row >> 1) & 15)) << 3;
    gload16h(wp2 + row * 128 + c8, Wl + f * 8);
  }
  __syncthreads();

  // stage2: conv16, out2 rows [t0-32, +64): 6 tiles, bufB -> bufA
  gstage<16, 6>(Wl, bufB, bufA, (tx == 0) ? 32 : 0, tid);
  __syncthreads();
  for (int f = tid; f < 4096; f += 256) {
    int row = f >> 4, l16 = f & 15;
    int c8 = (l16 ^ ((row >> 1) & 15)) << 3;
    gload16h(wp3 + row * 128 + c8, Wl + f * 8);
  }
  __syncthreads();

  // stage3: conv32, rows [t0, +64): 4 tiles, bufA -> bufB (a_l)
  gstage<32, 4>(Wl, bufA, bufB, 0, tid);
  __syncthreads();

  // linear from bufB (verified glin epilogue)
  const int l = tid & 63, w = tid >> 6;
  const int l15 = l & 15, lh = l >> 4;
  const int o0 = w * 32;
  f4 acc3[2][4] = {};
#pragma unroll
  for (int cb = 0; cb < 4; cb++) {
    const int c0 = cb * 32 + lh * 8;
    h8 a[2], bfr[4];
#pragma unroll
    for (int i2 = 0; i2 < 2; i2++) {
      int o = o0 + i2 * 16 + l15;
      a[i2] = *(const h8*)&linWh[o * 128 + c0];
    }
#pragma unroll
    for (int jt = 0; jt < 4; jt++) {
      int p = jt * 16 + l15;
      int cs = c0 ^ ((p & 15) << 3);
      bfr[jt] = *(const h8*)&bufB[p * 128 + cs];
    }
#pragma unroll
    for (int i2 = 0; i2 < 2; i2++)
#pragma unroll
      for (int jt = 0; jt < 4; jt++)
        acc3[i2][jt] = __builtin_amdgcn_mfma_f32_16x16x32_f16(
            a[i2], bfr[jt], acc3[i2][jt], 0, 0, 0);
  }

#pragma unroll
  for (int i2 = 0; i2 < 2; i2++) {
    int o = o0 + i2 * 16 + lh * 4;
    f4 bv = *(const f4*)&lbias[o];
#pragma unroll
    for (int jt = 0; jt < 4; jt++) {
      int t = t0 + jt * 16 + l15;
      f4 v = acc3[i2][jt];
      float4 sv = make_float4(v[0] + bv[0], v[1] + bv[1], v[2] + bv[2], v[3] + bv[3]);
      *(float4*)&outp[((size_t)n * TLEN + t) * CCH + o] = sv;
    }
  }
}

// ---------------------------------------------------------------------------
extern "C" void kernel_launch(void* const* d_in, const int* in_sizes, int n_in,
                              void* d_out, int out_size, void* d_ws, size_t ws_size,
                              hipStream_t stream) {
  const float* x  = (const float*)d_in[0];
  const float* r  = (const float*)d_in[1];
  // d_in[2] = f_out_same_in_size (==1)
  const float* w1 = (const float*)d_in[3];
  const float* b1 = (const float*)d_in[4];
  const float* w2 = (const float*)d_in[5];
  const float* b2 = (const float*)d_in[6];
  const float* fW = (const float*)d_in[7];
  const float* fb = (const float*)d_in[8];
  const float* lb = (const float*)d_in[9];
  const float* lw = (const float*)d_in[10];
  const float* lbias = (const float*)d_in[11];
  float* out = (float*)d_out;

  _Float16* h0    = (_Float16*)d_ws;        // 2,097,152 halves
  _Float16* h1    = h0 + 2097152;           // 2,097,152
  _Float16* Wsh   = h1 + 2097152;           // 393,216
  _Float16* linWh = Wsh + 393216;           // 16,384
  _Float16* Wg    = linWh + 16384;          // 1,572,864
  float*    fblb2 = (float*)(Wg + 1572864); // 98,304 floats

  k_init<<<1024, 256, 0, stream>>>(x, w1, w2, lw, fb, lb, h0, Wsh, linWh, fblb2);
  // gen (blocks 0..191) || pair1 (blocks 192..447)
  k_genpair<<<448, 256, 0, stream>>>(r, fW, fblb2, Wg, h0, h1, Wsh, b1, b2);

  const dim3 cg(16, 16);
  k_pair<2><<<cg, 256, 0, stream>>>(h1, h0, Wsh + 1 * 32768, Wsh + 4 * 32768,
                                    b1 + 128, b2 + 128);
  k_pair<4><<<cg, 256, 0, stream>>>(h0, h1, Wsh + 2 * 32768, Wsh + 5 * 32768,
                                    b1 + 256, b2 + 256);
  // fused group chain: conv8 -> conv16 -> conv32 -> linear
  k_group<<<cg, 256, 0, stream>>>(h1, out, Wg, linWh, lbias);
}